// Round 1
// baseline (420.755 us; speedup 1.0000x reference)
//
#include <hip/hip_runtime.h>
#include <hip/hip_bf16.h>

#define T_LEN 1024
#define BATCH 128
#define NCLS 80
#define TT 128

// ---------------- argmax over 80 classes per (t,b) ----------------
__global__ __launch_bounds__(256) void k_argmax(const float* __restrict__ inp, int* __restrict__ idx) {
  int n = blockIdx.x * 256 + threadIdx.x;   // n = t*BATCH + b, grid covers exactly T*B
  const float4* p4 = (const float4*)(inp + (size_t)n * NCLS);
  float best = -1e30f; int bi = 0;
  #pragma unroll
  for (int q = 0; q < NCLS/4; ++q) {
    float4 v = p4[q];
    if (v.x > best) { best = v.x; bi = 4*q+0; }
    if (v.y > best) { best = v.y; bi = 4*q+1; }
    if (v.z > best) { best = v.z; bi = 4*q+2; }
    if (v.w > best) { best = v.w; bi = 4*q+3; }
  }
  idx[n] = bi;
}

// ---------------- per-(b,o) constant from g_style channels ----------------
__global__ __launch_bounds__(128) void k_gconst(const float* __restrict__ w1, const float* __restrict__ b1,
    const float* __restrict__ gsty, float* __restrict__ Gfull, float* __restrict__ Gk0, float* __restrict__ Gk2) {
  int b = blockIdx.x, o = threadIdx.x;
  __shared__ float gl[256];
  for (int i = o; i < 256; i += 128) gl[i] = gsty[b*256 + i];
  __syncthreads();
  const float* wr = w1 + (size_t)o*1200 + 240;   // channels 80..335, taps interleaved
  float s0 = 0.f, s1 = 0.f, s2 = 0.f;
  for (int c = 0; c < 256; ++c) {
    float g = gl[c];
    s0 += wr[c*3+0]*g; s1 += wr[c*3+1]*g; s2 += wr[c*3+2]*g;
  }
  Gk0[b*128+o] = s0;
  Gk2[b*128+o] = s2;
  Gfull[b*128+o] = s0 + s1 + s2 + b1[o];
}

// ---------------- P[k][b][j][o] = sum_c2 char_style[b][j][c2] * w1[o][336+c2][k] ----------------
__global__ __launch_bounds__(256) void k_prep_char(const float* __restrict__ cs, const float* __restrict__ w1,
                                                   float* __restrict__ Pk) {
  int b = blockIdx.x, k = blockIdx.y;
  __shared__ float csl[80*64];
  __shared__ float wt[64][128];
  int tid = threadIdx.x;
  for (int f = tid; f < 80*64; f += 256) csl[f] = cs[(size_t)b*5120 + f];
  for (int f = tid; f < 64*128; f += 256) {
    int o = f & 127, c2 = f >> 7;
    wt[c2][o] = w1[(size_t)o*1200 + (336+c2)*3 + k];
  }
  __syncthreads();
  int o4 = (tid & 31) * 4;
  int jg = tid >> 5;                 // 0..7 -> 10 j's each
  for (int jj = 0; jj < 10; ++jj) {
    int j = jg*10 + jj;
    float a0=0.f,a1=0.f,a2=0.f,a3=0.f;
    #pragma unroll 8
    for (int c2 = 0; c2 < 64; ++c2) {
      float cv = csl[j*64 + c2];
      float4 wv = *(const float4*)&wt[c2][o4];
      a0 += cv*wv.x; a1 += cv*wv.y; a2 += cv*wv.z; a3 += cv*wv.w;
    }
    float* dst = Pk + (((size_t)k*BATCH + b)*80 + j)*128 + o4;
    *(float4*)dst = make_float4(a0,a1,a2,a3);
  }
}

// ---------------- conv1: dense part over 80 input channels + gathers + const ----------------
__global__ __launch_bounds__(256) void k_conv1(const float* __restrict__ inp,
    const float* __restrict__ w1, const int* __restrict__ idx,
    const float* __restrict__ Pk, const float* __restrict__ Gfull,
    const float* __restrict__ Gk0, const float* __restrict__ Gk2,
    float* __restrict__ y1) {
  int b = blockIdx.x;
  int t0 = blockIdx.y * TT;
  __shared__ float xs[16][TT+4];
  __shared__ float ws[3][16][132];
  __shared__ int idxs[TT+2];
  int tid = threadIdx.x;
  int tq = tid & 15, og = tid >> 4;         // 16 t-lanes x 16 o-groups
  float acc[8][8];
  #pragma unroll
  for (int i = 0; i < 8; ++i)
    #pragma unroll
    for (int j = 0; j < 8; ++j) acc[i][j] = 0.f;

  for (int i = tid; i < TT+2; i += 256) {
    int t = t0 + i - 1;
    idxs[i] = (t >= 0 && t < T_LEN) ? idx[t*BATCH + b] : -1;
  }

  for (int cc = 0; cc < 5; ++cc) {
    __syncthreads();
    for (int f = tid; f < 130*16; f += 256) {
      int r = f >> 4, ci = f & 15;
      int t = t0 + r - 1;
      float v = 0.f;
      if (t >= 0 && t < T_LEN) v = inp[((size_t)t*BATCH + b)*NCLS + cc*16 + ci];
      xs[ci][r] = v;
    }
    for (int f = tid; f < 6144; f += 256) {
      int o = f / 48, rem = f % 48;
      int ci = rem / 3, k = rem % 3;
      ws[k][ci][o] = w1[(size_t)o*1200 + (cc*16+ci)*3 + k];
    }
    __syncthreads();
    #pragma unroll
    for (int ci = 0; ci < 16; ++ci) {
      float xv[10];
      *(float4*)&xv[0] = *(const float4*)&xs[ci][tq*8];
      *(float4*)&xv[4] = *(const float4*)&xs[ci][tq*8+4];
      *(float2*)&xv[8] = *(const float2*)&xs[ci][tq*8+8];
      #pragma unroll
      for (int k = 0; k < 3; ++k) {
        float wv[8];
        *(float4*)&wv[0] = *(const float4*)&ws[k][ci][og*8];
        *(float4*)&wv[4] = *(const float4*)&ws[k][ci][og*8+4];
        #pragma unroll
        for (int i = 0; i < 8; ++i)
          #pragma unroll
          for (int j = 0; j < 8; ++j)
            acc[i][j] += wv[i]*xv[j+k];
      }
    }
  }

  // char-style gather contribution
  #pragma unroll
  for (int j = 0; j < 8; ++j) {
    int tl = tq*8 + j;
    #pragma unroll
    for (int k = 0; k < 3; ++k) {
      int jc = idxs[tl + k];
      if (jc >= 0) {
        const float4* pr = (const float4*)(Pk + (((size_t)k*BATCH + b)*80 + jc)*128 + og*8);
        float4 p0 = pr[0], p1 = pr[1];
        acc[0][j] += p0.x; acc[1][j] += p0.y; acc[2][j] += p0.z; acc[3][j] += p0.w;
        acc[4][j] += p1.x; acc[5][j] += p1.y; acc[6][j] += p1.z; acc[7][j] += p1.w;
      }
    }
  }

  int tb = t0 + tq*8;
  #pragma unroll
  for (int i = 0; i < 8; ++i) {
    int o = og*8 + i;
    float g  = Gfull[b*128 + o];
    float g0 = Gk0[b*128 + o];
    float g2 = Gk2[b*128 + o];
    float vals[8];
    #pragma unroll
    for (int j = 0; j < 8; ++j) {
      float add = g;
      int t = tb + j;
      if (t == 0) add -= g0;
      if (t == T_LEN-1) add -= g2;
      vals[j] = acc[i][j] + add;
    }
    float* dst = y1 + ((size_t)b*128 + o)*T_LEN + tb;
    *(float4*)dst       = make_float4(vals[0],vals[1],vals[2],vals[3]);
    *(float4*)(dst + 4) = make_float4(vals[4],vals[5],vals[6],vals[7]);
  }
}

// ---------------- group-norm stats: per (b, group) mean & rstd ----------------
template<int CPG>
__global__ __launch_bounds__(256) void k_stats(const float* __restrict__ y, float2* __restrict__ gst) {
  int bg = blockIdx.x;                       // b*32 + g ; group rows contiguous
  const float4* p = (const float4*)(y + (size_t)bg * CPG * T_LEN);
  float s = 0.f, sq = 0.f;
  #pragma unroll
  for (int i = 0; i < CPG; ++i) {
    float4 v = p[i*256 + threadIdx.x];
    s  += v.x+v.y+v.z+v.w;
    sq += v.x*v.x+v.y*v.y+v.z*v.z+v.w*v.w;
  }
  #pragma unroll
  for (int off = 32; off > 0; off >>= 1) { s += __shfl_down(s, off); sq += __shfl_down(sq, off); }
  __shared__ float ps[4], pq[4];
  int w = threadIdx.x >> 6;
  if ((threadIdx.x & 63) == 0) { ps[w] = s; pq[w] = sq; }
  __syncthreads();
  if (threadIdx.x == 0) {
    s  = ps[0]+ps[1]+ps[2]+ps[3];
    sq = pq[0]+pq[1]+pq[2]+pq[3];
    float invn = 1.f / (float)(CPG * T_LEN);
    float m = s * invn;
    float var = sq * invn - m*m;
    gst[bg] = make_float2(m, rsqrtf(var + 1e-5f));
  }
}

// ---------------- middle convs: normalize+relu previous layer on load ----------------
template<int CIN, int CO, int CPG>
__global__ __launch_bounds__(256) void k_conv_mid(const float* __restrict__ x,
    const float* __restrict__ w, const float* __restrict__ bias,
    const float2* __restrict__ gst, const float* __restrict__ gs,
    const float* __restrict__ gb, float* __restrict__ y) {
  constexpr int OPT = CO / 16;
  int b = blockIdx.x;
  int t0 = blockIdx.y * TT;
  __shared__ float xs[16][TT+4];
  __shared__ float ws[3][16][CO+4];
  __shared__ float aL[CIN], dL[CIN];
  int tid = threadIdx.x;
  int tq = tid & 15, og = tid >> 4;
  float acc[OPT][8];
  #pragma unroll
  for (int i = 0; i < OPT; ++i)
    #pragma unroll
    for (int j = 0; j < 8; ++j) acc[i][j] = 0.f;

  for (int c = tid; c < CIN; c += 256) {
    float2 st = gst[b*32 + c/CPG];
    float a = st.y * gs[c];
    aL[c] = a; dL[c] = gb[c] - st.x * a;
  }

  for (int cc = 0; cc < CIN/16; ++cc) {
    __syncthreads();
    for (int f = tid; f < 130*16; f += 256) {
      int r = f >> 4, ci = f & 15;
      int t = t0 + r - 1;
      int c = cc*16 + ci;
      float v = 0.f;
      if (t >= 0 && t < T_LEN) {
        v = x[((size_t)b*CIN + c)*T_LEN + t];
        v = fmaxf(0.f, v*aL[c] + dL[c]);
      }
      xs[ci][r] = v;
    }
    for (int f = tid; f < 48*CO; f += 256) {
      int o = f / 48, rem = f % 48;
      int ci = rem / 3, k = rem % 3;
      ws[k][ci][o] = w[(size_t)o*(CIN*3) + (cc*16+ci)*3 + k];
    }
    __syncthreads();
    #pragma unroll
    for (int ci = 0; ci < 16; ++ci) {
      float xv[10];
      *(float4*)&xv[0] = *(const float4*)&xs[ci][tq*8];
      *(float4*)&xv[4] = *(const float4*)&xs[ci][tq*8+4];
      *(float2*)&xv[8] = *(const float2*)&xs[ci][tq*8+8];
      #pragma unroll
      for (int k = 0; k < 3; ++k) {
        float wv[OPT];
        if constexpr (OPT == 4) {
          *(float4*)&wv[0] = *(const float4*)&ws[k][ci][og*4];
        } else {
          *(float2*)&wv[0] = *(const float2*)&ws[k][ci][og*2];
        }
        #pragma unroll
        for (int i = 0; i < OPT; ++i)
          #pragma unroll
          for (int j = 0; j < 8; ++j)
            acc[i][j] += wv[i]*xv[j+k];
      }
    }
  }

  int tb = t0 + tq*8;
  #pragma unroll
  for (int i = 0; i < OPT; ++i) {
    int o = og*OPT + i;
    float bi_ = bias[o];
    float* dst = y + ((size_t)b*CO + o)*T_LEN + tb;
    *(float4*)dst       = make_float4(acc[i][0]+bi_, acc[i][1]+bi_, acc[i][2]+bi_, acc[i][3]+bi_);
    *(float4*)(dst + 4) = make_float4(acc[i][4]+bi_, acc[i][5]+bi_, acc[i][6]+bi_, acc[i][7]+bi_);
  }
}

// ---------------- final: gn3+relu, 1x1 conv to 1 channel, affine, transpose ----------------
__global__ __launch_bounds__(256) void k_final(const float* __restrict__ y3, const float2* __restrict__ gst3,
    const float* __restrict__ s3, const float* __restrict__ b3,
    const float* __restrict__ w4, const float* __restrict__ b4,
    const float* __restrict__ mn, const float* __restrict__ sd, float* __restrict__ out) {
  int b = blockIdx.x;
  int t = blockIdx.y * 256 + threadIdx.x;
  __shared__ float wl[32], al[32], dl[32];
  if (threadIdx.x < 32) {
    int c = threadIdx.x;
    float2 st = gst3[b*32 + c];       // cpg==1: group == channel
    float a = st.y * s3[c];
    al[c] = a; dl[c] = b3[c] - st.x * a; wl[c] = w4[c];
  }
  __syncthreads();
  float s = b4[0];
  #pragma unroll 8
  for (int c = 0; c < 32; ++c) {
    float v = y3[((size_t)b*32 + c)*T_LEN + t];
    v = fmaxf(0.f, v*al[c] + dl[c]);
    s += wl[c]*v;
  }
  out[(size_t)t*BATCH + b] = s*sd[0] + mn[0];
}

extern "C" void kernel_launch(void* const* d_in, const int* in_sizes, int n_in,
                              void* d_out, int out_size, void* d_ws, size_t ws_size,
                              hipStream_t stream) {
  const float* inp  = (const float*)d_in[0];
  const float* gsty = (const float*)d_in[1];
  // d_in[2] spacing_style: unused by reference
  const float* cs   = (const float*)d_in[3];
  const float* w1   = (const float*)d_in[4];
  const float* b1   = (const float*)d_in[5];
  const float* gn1s = (const float*)d_in[6];
  const float* gn1b = (const float*)d_in[7];
  const float* w2   = (const float*)d_in[8];
  const float* b2   = (const float*)d_in[9];
  const float* gn2s = (const float*)d_in[10];
  const float* gn2b = (const float*)d_in[11];
  const float* w3   = (const float*)d_in[12];
  const float* b3   = (const float*)d_in[13];
  const float* gn3s = (const float*)d_in[14];
  const float* gn3b = (const float*)d_in[15];
  const float* w4   = (const float*)d_in[16];
  const float* b4   = (const float*)d_in[17];
  const float* mn   = (const float*)d_in[18];
  const float* sd   = (const float*)d_in[19];
  float* out = (float*)d_out;
  float* ws  = (float*)d_ws;

  int*   idx   = (int*)ws;                               // 131072 ints
  float* Pk    = ws + 131072;                            // 3*128*80*128
  float* Gfull = Pk + (size_t)3*128*80*128;              // 16384
  float* Gk0   = Gfull + 16384;
  float* Gk2   = Gk0 + 16384;
  float* y1    = Gk2 + 16384;                            // 128*128*1024
  float* y2    = y1 + (size_t)128*128*1024;              // 128*64*1024
  float* y3    = y2 + (size_t)128*64*1024;               // 128*32*1024
  float2* gs1  = (float2*)(y3 + (size_t)128*32*1024);    // 4096 float2
  float2* gs2  = gs1 + 4096;
  float2* gs3  = gs2 + 4096;

  k_argmax<<<512, 256, 0, stream>>>(inp, idx);
  k_gconst<<<128, 128, 0, stream>>>(w1, b1, gsty, Gfull, Gk0, Gk2);
  k_prep_char<<<dim3(128,3), 256, 0, stream>>>(cs, w1, Pk);
  k_conv1<<<dim3(128,8), 256, 0, stream>>>(inp, w1, idx, Pk, Gfull, Gk0, Gk2, y1);
  k_stats<4><<<4096, 256, 0, stream>>>(y1, gs1);
  k_conv_mid<128,64,4><<<dim3(128,8), 256, 0, stream>>>(y1, w2, b2, gs1, gn1s, gn1b, y2);
  k_stats<2><<<4096, 256, 0, stream>>>(y2, gs2);
  k_conv_mid<64,32,2><<<dim3(128,8), 256, 0, stream>>>(y2, w3, b3, gs2, gn2s, gn2b, y3);
  k_stats<1><<<4096, 256, 0, stream>>>(y3, gs3);
  k_final<<<dim3(128,4), 256, 0, stream>>>(y3, gs3, gn3s, gn3b, w4, b4, mn, sd, out);
}

// Round 2
// 124.331 us; speedup vs baseline: 3.3841x; 3.3841x over previous
//
#include <hip/hip_runtime.h>
#include <hip/hip_bf16.h>

#define T_LEN 1024
#define BATCH 128

typedef __attribute__((ext_vector_type(8))) short short8;
typedef __attribute__((ext_vector_type(4))) float f32x4;

__device__ __forceinline__ float b2f(ushort u) {
  union { uint i; float f; } c; c.i = ((uint)u) << 16; return c.f;
}
__device__ __forceinline__ ushort f2b(float f) {
  __hip_bfloat16 h = __float2bfloat16(f);
  return *reinterpret_cast<ushort*>(&h);
}

// ---------------- argmax over 80 classes per (t,b) ----------------
__global__ __launch_bounds__(256) void k_argmax(const float* __restrict__ inp, int* __restrict__ idx) {
  int n = blockIdx.x * 256 + threadIdx.x;
  const float4* p4 = (const float4*)(inp + (size_t)n * 80);
  float best = -1e30f; int bi = 0;
  #pragma unroll
  for (int q = 0; q < 20; ++q) {
    float4 v = p4[q];
    if (v.x > best) { best = v.x; bi = 4*q+0; }
    if (v.y > best) { best = v.y; bi = 4*q+1; }
    if (v.z > best) { best = v.z; bi = 4*q+2; }
    if (v.w > best) { best = v.w; bi = 4*q+3; }
  }
  idx[n] = bi;
}

// ---------------- per-(b,o) constant from g_style channels (exact fp32) ----------------
__global__ __launch_bounds__(128) void k_gconst(const float* __restrict__ w1, const float* __restrict__ b1,
    const float* __restrict__ gsty, float* __restrict__ Gfull, float* __restrict__ Gk0, float* __restrict__ Gk2) {
  int b = blockIdx.x, o = threadIdx.x;
  __shared__ float gl[256];
  for (int i = o; i < 256; i += 128) gl[i] = gsty[b*256 + i];
  __syncthreads();
  const float* wr = w1 + (size_t)o*1200 + 240;   // channels 80..335
  float s0 = 0.f, s1 = 0.f, s2 = 0.f;
  for (int c = 0; c < 256; ++c) {
    float g = gl[c];
    s0 += wr[c*3+0]*g; s1 += wr[c*3+1]*g; s2 += wr[c*3+2]*g;
  }
  Gk0[b*128+o] = s0;
  Gk2[b*128+o] = s2;
  Gfull[b*128+o] = s0 + s1 + s2 + b1[o];
}

// ---------------- pack weights to bf16 [O][3][Cpad] ----------------
__global__ __launch_bounds__(256) void k_prepw(const float* __restrict__ w1, const float* __restrict__ w2,
    const float* __restrict__ w3, ushort* __restrict__ Wp1, ushort* __restrict__ Wp2, ushort* __restrict__ Wp3) {
  int e = blockIdx.x*256 + threadIdx.x;
  if (e < 128*3*160) {
    int o = e / 480, r = e % 480, k = r / 160, c = r % 160;
    float v = 0.f;
    if (c < 80)       v = w1[(size_t)o*1200 + c*3 + k];
    else if (c < 144) v = w1[(size_t)o*1200 + (336 + c - 80)*3 + k];
    Wp1[e] = f2b(v);
  } else if (e < 128*3*160 + 64*3*128) {
    int e2 = e - 128*3*160;
    int o = e2/384, r = e2%384, k = r/128, c = r%128;
    Wp2[e2] = f2b(w2[(size_t)o*384 + c*3 + k]);
  } else if (e < 128*3*160 + 64*3*128 + 32*3*64) {
    int e3 = e - (128*3*160 + 64*3*128);
    int o = e3/192, r = e3%192, k = r/64, c = r%64;
    Wp3[e3] = f2b(w3[(size_t)o*192 + c*3 + k]);
  }
}

// ---------------- conv1 MFMA: 144 eff. input channels (80 input + 64 gathered char), pad to 160 ----------------
__global__ __launch_bounds__(256) void k_conv1m(const float* __restrict__ inp,
    const ushort* __restrict__ Wp1, const int* __restrict__ idx, const float* __restrict__ cs,
    const float* __restrict__ gfull, const float* __restrict__ gk0, const float* __restrict__ gk2,
    ushort* __restrict__ y1, float2* __restrict__ part1) {
  __shared__ __align__(16) ushort Xs[130][40];
  __shared__ __align__(16) ushort Ws[128][104];
  __shared__ float gf[128], g0[128], g2[128];
  __shared__ float ps[4][128], pq[4][128];
  int b = blockIdx.x, t0 = blockIdx.y*128;
  int tid = threadIdx.x, lane = tid & 63, wave = tid >> 6;
  int wt = wave*32;
  f32x4 acc[2][8];
  #pragma unroll
  for (int mt = 0; mt < 2; ++mt)
    #pragma unroll
    for (int nt = 0; nt < 8; ++nt) { f32x4 z = {0.f,0.f,0.f,0.f}; acc[mt][nt] = z; }

  if (tid < 128) { gf[tid] = gfull[b*128+tid]; g0[tid] = gk0[b*128+tid]; g2[tid] = gk2[b*128+tid]; }

  for (int cc = 0; cc < 5; ++cc) {
    __syncthreads();
    // fill Xs[r][ci]: t = t0-1+r, channel = cc*32+ci  (0..79 input, 80..143 char gather, >=144 zero)
    for (int task = tid; task < 520; task += 256) {
      int r = task >> 2, oc = task & 3;
      int c8 = cc*32 + oc*8;
      int t = t0 - 1 + r;
      float f[8] = {0.f,0.f,0.f,0.f,0.f,0.f,0.f,0.f};
      if (t >= 0 && t < T_LEN && c8 < 144) {
        const float* src;
        if (c8 < 80) src = inp + ((size_t)t*BATCH + b)*80 + c8;
        else {
          int jc = idx[t*BATCH + b];
          src = cs + ((size_t)b*80 + jc)*64 + (c8 - 80);
        }
        float4 u0 = *(const float4*)src, u1 = *(const float4*)(src+4);
        f[0]=u0.x; f[1]=u0.y; f[2]=u0.z; f[3]=u0.w;
        f[4]=u1.x; f[5]=u1.y; f[6]=u1.z; f[7]=u1.w;
      }
      uint* dst = (uint*)&Xs[r][oc*8];
      dst[0] = f2b(f[0]) | ((uint)f2b(f[1])<<16);
      dst[1] = f2b(f[2]) | ((uint)f2b(f[3])<<16);
      dst[2] = f2b(f[4]) | ((uint)f2b(f[5])<<16);
      dst[3] = f2b(f[6]) | ((uint)f2b(f[7])<<16);
    }
    // fill Ws: 128 rows x 96 shorts (3 taps x 32 c)
    for (int task = tid; task < 128*12; task += 256) {
      int o = task / 12, seg = task % 12;
      int k = seg >> 2, oct = seg & 3;
      *(short8*)&Ws[o][seg*8] = *(const short8*)(Wp1 + ((size_t)o*3 + k)*160 + cc*32 + oct*8);
    }
    __syncthreads();
    int ln = lane & 15, lq = lane >> 4;
    #pragma unroll
    for (int k = 0; k < 3; ++k) {
      short8 a0 = *(const short8*)&Xs[wt + ln + k][lq*8];
      short8 a1 = *(const short8*)&Xs[wt + 16 + ln + k][lq*8];
      #pragma unroll
      for (int nt = 0; nt < 8; ++nt) {
        short8 bb = *(const short8*)&Ws[nt*16 + ln][k*32 + lq*8];
        acc[0][nt] = __builtin_amdgcn_mfma_f32_16x16x32_bf16(a0, bb, acc[0][nt], 0, 0, 0);
        acc[1][nt] = __builtin_amdgcn_mfma_f32_16x16x32_bf16(a1, bb, acc[1][nt], 0, 0, 0);
      }
    }
  }
  // epilogue: add g_style const (+edge corr), store bf16, partial GN stats
  int ln = lane & 15, lq = lane >> 4;
  #pragma unroll
  for (int nt = 0; nt < 8; ++nt) {
    int o = nt*16 + ln;
    float add = gf[o];
    float s = 0.f, q = 0.f;
    #pragma unroll
    for (int mt = 0; mt < 2; ++mt) {
      int tb = t0 + wt + mt*16 + lq*4;
      float vv[4];
      #pragma unroll
      for (int r = 0; r < 4; ++r) {
        float v = acc[mt][nt][r] + add;
        int t = tb + r;
        if (t == 0) v -= g0[o];
        if (t == T_LEN-1) v -= g2[o];
        vv[r] = v; s += v; q += v*v;
      }
      uint2 pk;
      pk.x = f2b(vv[0]) | ((uint)f2b(vv[1])<<16);
      pk.y = f2b(vv[2]) | ((uint)f2b(vv[3])<<16);
      *(uint2*)(y1 + ((size_t)b*128 + o)*T_LEN + tb) = pk;
    }
    s += __shfl_xor(s, 16); s += __shfl_xor(s, 32);
    q += __shfl_xor(q, 16); q += __shfl_xor(q, 32);
    if (lane < 16) { ps[wave][o] = s; pq[wave][o] = q; }
  }
  __syncthreads();
  if (tid < 128) {
    float S = ps[0][tid]+ps[1][tid]+ps[2][tid]+ps[3][tid];
    float Q = pq[0][tid]+pq[1][tid]+pq[2][tid]+pq[3][tid];
    part1[((size_t)b*128 + tid)*8 + blockIdx.y] = make_float2(S, Q);
  }
}

// ---------------- stats: partials -> per-channel (a, d) affine ----------------
template<int CO, int CPG>
__global__ __launch_bounds__(256) void k_gstats(const float2* __restrict__ part,
    const float* __restrict__ gs, const float* __restrict__ gb, float2* __restrict__ gstc) {
  int b = blockIdx.x, tid = threadIdx.x;
  __shared__ float ss[CO], qq[CO];
  if (tid < CO) {
    float S = 0.f, Q = 0.f;
    const float2* p = part + (size_t)(b*CO + tid)*8;
    #pragma unroll
    for (int j = 0; j < 8; ++j) { float2 v = p[j]; S += v.x; Q += v.y; }
    ss[tid] = S; qq[tid] = Q;
  }
  __syncthreads();
  if (tid < 32) {
    float S = 0.f, Q = 0.f;
    #pragma unroll
    for (int ci = 0; ci < CPG; ++ci) { S += ss[tid*CPG+ci]; Q += qq[tid*CPG+ci]; }
    float invn = 1.f / (float)(CPG * T_LEN);
    float m = S * invn;
    float var = Q * invn - m*m;
    float rs = rsqrtf(var + 1e-5f);
    for (int ci = 0; ci < CPG; ++ci) {
      int c = tid*CPG + ci;
      float a = rs * gs[c];
      gstc[b*CO + c] = make_float2(a, gb[c] - m*a);
    }
  }
}

// ---------------- mid convs MFMA: normalize+relu prev layer on LDS fill ----------------
template<int CIN, int CO>
__global__ __launch_bounds__(256) void k_convmid(const ushort* __restrict__ xin,
    const ushort* __restrict__ Wp, const float* __restrict__ bias,
    const float2* __restrict__ gstc, ushort* __restrict__ yout, float2* __restrict__ part) {
  constexpr int NT = CO/16, NC = CIN/32;
  __shared__ __align__(16) ushort Xs[130][40];
  __shared__ __align__(16) ushort Ws[CO][104];
  __shared__ float2 aff[CIN];
  __shared__ float bl[CO];
  __shared__ float ps[4][CO], pq[4][CO];
  int b = blockIdx.x, t0 = blockIdx.y*128;
  int tid = threadIdx.x, lane = tid & 63, wave = tid >> 6;
  int wt = wave*32;
  f32x4 acc[2][NT];
  #pragma unroll
  for (int mt = 0; mt < 2; ++mt)
    #pragma unroll
    for (int nt = 0; nt < NT; ++nt) { f32x4 z = {0.f,0.f,0.f,0.f}; acc[mt][nt] = z; }

  if (tid < CIN) aff[tid] = gstc[b*CIN + tid];
  if (tid < CO)  bl[tid]  = bias[tid];

  for (int cc = 0; cc < NC; ++cc) {
    __syncthreads();
    {
      // main rows 1..128 from aligned t-octets
      int cp = (tid & 15)*2, j = tid >> 4;
      int c = cc*32 + cp;
      const ushort* s0 = xin + ((size_t)b*CIN + c)*T_LEN + t0 + j*8;
      short8 v0 = *(const short8*)s0;
      short8 v1 = *(const short8*)(s0 + T_LEN);
      float2 A0 = aff[c], A1 = aff[c+1];
      #pragma unroll
      for (int e = 0; e < 8; ++e) {
        float f0 = fmaxf(0.f, b2f((ushort)v0[e])*A0.x + A0.y);
        float f1 = fmaxf(0.f, b2f((ushort)v1[e])*A1.x + A1.y);
        *(uint*)&Xs[1 + j*8 + e][cp] = f2b(f0) | ((uint)f2b(f1) << 16);
      }
      // edge rows 0 and 129
      if (tid < 64) {
        int r = (tid < 32) ? 0 : 129;
        int ci = tid & 31;
        int t = t0 - 1 + r;
        ushort val = 0;
        if (t >= 0 && t < T_LEN) {
          float2 A = aff[cc*32 + ci];
          float f = b2f(xin[((size_t)b*CIN + cc*32 + ci)*T_LEN + t]);
          val = f2b(fmaxf(0.f, f*A.x + A.y));
        }
        Xs[r][ci] = val;
      }
    }
    for (int task = tid; task < CO*12; task += 256) {
      int o = task / 12, seg = task % 12;
      int k = seg >> 2, oct = seg & 3;
      *(short8*)&Ws[o][seg*8] = *(const short8*)(Wp + ((size_t)o*3 + k)*CIN + cc*32 + oct*8);
    }
    __syncthreads();
    int ln = lane & 15, lq = lane >> 4;
    #pragma unroll
    for (int k = 0; k < 3; ++k) {
      short8 a0 = *(const short8*)&Xs[wt + ln + k][lq*8];
      short8 a1 = *(const short8*)&Xs[wt + 16 + ln + k][lq*8];
      #pragma unroll
      for (int nt = 0; nt < NT; ++nt) {
        short8 bb = *(const short8*)&Ws[nt*16 + ln][k*32 + lq*8];
        acc[0][nt] = __builtin_amdgcn_mfma_f32_16x16x32_bf16(a0, bb, acc[0][nt], 0, 0, 0);
        acc[1][nt] = __builtin_amdgcn_mfma_f32_16x16x32_bf16(a1, bb, acc[1][nt], 0, 0, 0);
      }
    }
  }
  int ln = lane & 15, lq = lane >> 4;
  #pragma unroll
  for (int nt = 0; nt < NT; ++nt) {
    int o = nt*16 + ln;
    float add = bl[o];
    float s = 0.f, q = 0.f;
    #pragma unroll
    for (int mt = 0; mt < 2; ++mt) {
      int tb = t0 + wt + mt*16 + lq*4;
      float vv[4];
      #pragma unroll
      for (int r = 0; r < 4; ++r) {
        float v = acc[mt][nt][r] + add;
        vv[r] = v; s += v; q += v*v;
      }
      uint2 pk;
      pk.x = f2b(vv[0]) | ((uint)f2b(vv[1])<<16);
      pk.y = f2b(vv[2]) | ((uint)f2b(vv[3])<<16);
      *(uint2*)(yout + ((size_t)b*CO + o)*T_LEN + tb) = pk;
    }
    s += __shfl_xor(s, 16); s += __shfl_xor(s, 32);
    q += __shfl_xor(q, 16); q += __shfl_xor(q, 32);
    if (lane < 16) { ps[wave][o] = s; pq[wave][o] = q; }
  }
  __syncthreads();
  if (tid < CO) {
    float S = ps[0][tid]+ps[1][tid]+ps[2][tid]+ps[3][tid];
    float Q = pq[0][tid]+pq[1][tid]+pq[2][tid]+pq[3][tid];
    part[((size_t)b*CO + tid)*8 + blockIdx.y] = make_float2(S, Q);
  }
}

// ---------------- final: gn3+relu, 1x1 conv, affine, transpose ----------------
__global__ __launch_bounds__(256) void k_final(const ushort* __restrict__ y3, const float2* __restrict__ gstc3,
    const float* __restrict__ w4, const float* __restrict__ b4,
    const float* __restrict__ mn, const float* __restrict__ sd, float* __restrict__ out) {
  int b = blockIdx.x;
  int t = blockIdx.y * 256 + threadIdx.x;
  __shared__ float wl[32];
  __shared__ float2 al[32];
  if (threadIdx.x < 32) { al[threadIdx.x] = gstc3[b*32 + threadIdx.x]; wl[threadIdx.x] = w4[threadIdx.x]; }
  __syncthreads();
  float s = b4[0];
  #pragma unroll 8
  for (int c = 0; c < 32; ++c) {
    float v = b2f(y3[((size_t)b*32 + c)*T_LEN + t]);
    float2 A = al[c];
    s += wl[c] * fmaxf(0.f, v*A.x + A.y);
  }
  out[(size_t)t*BATCH + b] = s*sd[0] + mn[0];
}

extern "C" void kernel_launch(void* const* d_in, const int* in_sizes, int n_in,
                              void* d_out, int out_size, void* d_ws, size_t ws_size,
                              hipStream_t stream) {
  const float* inp  = (const float*)d_in[0];
  const float* gsty = (const float*)d_in[1];
  const float* cs   = (const float*)d_in[3];
  const float* w1   = (const float*)d_in[4];
  const float* b1   = (const float*)d_in[5];
  const float* gn1s = (const float*)d_in[6];
  const float* gn1b = (const float*)d_in[7];
  const float* w2   = (const float*)d_in[8];
  const float* b2   = (const float*)d_in[9];
  const float* gn2s = (const float*)d_in[10];
  const float* gn2b = (const float*)d_in[11];
  const float* w3   = (const float*)d_in[12];
  const float* b3   = (const float*)d_in[13];
  const float* gn3s = (const float*)d_in[14];
  const float* gn3b = (const float*)d_in[15];
  const float* w4   = (const float*)d_in[16];
  const float* b4   = (const float*)d_in[17];
  const float* mn   = (const float*)d_in[18];
  const float* sd   = (const float*)d_in[19];
  float* out = (float*)d_out;
  float* ws  = (float*)d_ws;

  int*    idx = (int*)ws;                          // 131072 ints
  ushort* Wp1 = (ushort*)(ws + 131072);            // 61440 shorts
  ushort* Wp2 = Wp1 + 61440;                       // 24576
  ushort* Wp3 = Wp2 + 24576;                       // 6144
  float* Gfull = ws + 131072 + 46080;
  float* Gk0   = Gfull + 16384;
  float* Gk2   = Gk0 + 16384;
  ushort* y1 = (ushort*)(Gk2 + 16384);             // 128*128*1024
  ushort* y2 = y1 + (size_t)128*128*1024;          // 128*64*1024
  ushort* y3 = y2 + (size_t)128*64*1024;           // 128*32*1024
  float2* part1 = (float2*)(y3 + (size_t)128*32*1024);  // 128*128*8
  float2* part2 = part1 + 131072;                  // 128*64*8
  float2* part3 = part2 + 65536;                   // 128*32*8
  float2* gstc1 = part3 + 32768;                   // 128*128
  float2* gstc2 = gstc1 + 16384;                   // 128*64
  float2* gstc3 = gstc2 + 8192;                    // 128*32

  k_argmax<<<512, 256, 0, stream>>>(inp, idx);
  k_gconst<<<128, 128, 0, stream>>>(w1, b1, gsty, Gfull, Gk0, Gk2);
  k_prepw<<<360, 256, 0, stream>>>(w1, w2, w3, Wp1, Wp2, Wp3);
  k_conv1m<<<dim3(128,8), 256, 0, stream>>>(inp, Wp1, idx, cs, Gfull, Gk0, Gk2, y1, part1);
  k_gstats<128,4><<<128, 256, 0, stream>>>(part1, gn1s, gn1b, gstc1);
  k_convmid<128,64><<<dim3(128,8), 256, 0, stream>>>(y1, Wp2, b2, gstc1, y2, part2);
  k_gstats<64,2><<<128, 256, 0, stream>>>(part2, gn2s, gn2b, gstc2);
  k_convmid<64,32><<<dim3(128,8), 256, 0, stream>>>(y2, Wp3, b3, gstc2, y3, part3);
  k_gstats<32,1><<<128, 256, 0, stream>>>(part3, gn3s, gn3b, gstc3);
  k_final<<<dim3(128,4), 256, 0, stream>>>(y3, gstc3, w4, b4, mn, sd, out);
}